// Round 11
// baseline (236.184 us; speedup 1.0000x reference)
//
#include <hip/hip_runtime.h>

// ---------------------------------------------------------------------------
// SelfAttentionPairDim2: B=4, N=256, M=256, D=64. Output [4,256,256,64].
// One workgroup (4 waves) per (b,i); fused MFMA pipeline:
//   QKV proj -> S=relu(K Q^T/8) -> rownorm -> P V -> out proj -> +x -> LN
//
// R11: remove the ctx->out-proj LDS round-trip (the last per-mt barrier
// except the y stage). Ledger: R6 in-register P fragment (+18us), R10
// preload/merge (+14us metric) -- both "spend VGPRs to shorten the serial
// chain"; this round applies the SAME verified permutation to ctx:
//  * ctx^T -> cf fragment in-register: pc[dt][2] = pkbf pairs of
//    ctxa[dt]*inv; cf0/cf1 dword j = shfl(pc[dt(hsel)][j&1], srcA/srcB).
//    Identical srcA/srcB/hsel as the P build (derivation in analysis).
//    Replaces 16 ds_write + __syncthreads + 2 ds_read_b128 per mt.
//    Barriers/block: 9 -> 5 (bf16), 1 (fp32).
//  * Residual X loads hoisted before the ct loop (latency hides under
//    the QK/PV chain).
//  * Numerics bit-identical (same f2bf(ctx*inv) values, new transport).
// Frozen: 256 thr / 4 waves / 1 block/CU (any >1 wave/SIMD fails O(1)).
// Kept: merged phase 1 (X loaded once), all weights preloaded, swapped
// QK^T, in-register P fragment, unroll-1 ct loop, single-dispatch host.
// ---------------------------------------------------------------------------

using bh8   = __attribute__((ext_vector_type(8))) short;
using f32x4 = __attribute__((ext_vector_type(4))) float;

#define MFMA(a, b, c) __builtin_amdgcn_mfma_f32_16x16x32_bf16((a), (b), (c), 0, 0, 0)

#define SQ_STRIDE  72   // elements; 144 B rows (16B aligned)
#define SVT_STRIDE 264  // elements; 528 B rows (16B aligned)
#define SY_STRIDE  72
#define STG_ELTS   (16 * 72)  // 1152 per wave (y staging only now)
#define LDS_BYTES  ((256 * SQ_STRIDE * 2 + 64 * SVT_STRIDE + 4 * STG_ELTS) * 2)  // 116736 B

__device__ __forceinline__ float bf2f(unsigned short u) {
  union { unsigned int i; float f; } x;
  x.i = ((unsigned int)u) << 16;
  return x.f;
}
__device__ __forceinline__ unsigned short f2bf(float f) {
  union { float f; unsigned int i; } x;
  x.f = f;
  unsigned int u = x.i + 0x7FFFu + ((x.i >> 16) & 1u);  // RNE
  return (unsigned short)(u >> 16);
}
__device__ __forceinline__ int pkbf(float lo, float hi) {
  return (int)(((unsigned int)f2bf(hi) << 16) | (unsigned int)f2bf(lo));
}

template <int FP32>
__device__ __forceinline__ bh8 g_load8(const void* base, size_t idx) {
  if constexpr (FP32) {
    const float* p = (const float*)base + idx;
    float4 a = *(const float4*)p;
    float4 b = *(const float4*)(p + 4);
    bh8 r;
    r[0] = (short)f2bf(a.x); r[1] = (short)f2bf(a.y);
    r[2] = (short)f2bf(a.z); r[3] = (short)f2bf(a.w);
    r[4] = (short)f2bf(b.x); r[5] = (short)f2bf(b.y);
    r[6] = (short)f2bf(b.z); r[7] = (short)f2bf(b.w);
    return r;
  } else {
    return *(const bh8*)((const unsigned short*)base + idx);
  }
}
template <int FP32>
__device__ __forceinline__ float g_loadf(const void* base, size_t idx) {
  if constexpr (FP32) return ((const float*)base)[idx];
  else return bf2f(((const unsigned short*)base)[idx]);
}

template <int FP32>
__global__ __launch_bounds__(256, 1) void pairattn(
    const void* __restrict__ Xv,
    const void* __restrict__ Wqv, const void* __restrict__ bqv,
    const void* __restrict__ Wkv, const void* __restrict__ bkv,
    const void* __restrict__ Wvv, const void* __restrict__ bvv,
    const void* __restrict__ Wov, const void* __restrict__ bov,
    const void* __restrict__ lngv, const void* __restrict__ lnbv,
    void* __restrict__ Outv) {
  const int tid  = threadIdx.x;
  const int lane = tid & 63;

  // ---- dtype detection (block-uniform, deterministic; guard for the
  // dual-launch fallback path) ----
  {
    const unsigned short* xu = (const unsigned short*)Xv + (lane << 4);
    int huge = 0;
#pragma unroll
    for (int j = 0; j < 16; ++j) {
      unsigned e = ((unsigned)xu[j] >> 7) & 0xFFu;
      huge |= (e >= 0x90u) ? 1 : 0;
    }
    const bool isf32 = (__ballot(huge) != 0ULL);
    if (isf32 != (FP32 != 0)) return;  // uniform exit, before any barrier
  }

  extern __shared__ unsigned short sm[];
  unsigned short* sQ  = sm;                        // 256 x 72
  unsigned short* sK  = sQ + 256 * SQ_STRIDE;      // 256 x 72
  unsigned short* sVt = sK + 256 * SQ_STRIDE;      // 64 x 264 (V transposed)
  unsigned short* sSt = sVt + 64 * SVT_STRIDE;     // 4 x 1152 wave-private

  const int wv  = tid >> 6;
  const int q4  = lane >> 4;
  const int l16 = lane & 15;
  const int m0w = wv << 6;
  const size_t xoff = (size_t)blockIdx.x * 16384;
  unsigned short* stg = sSt + wv * STG_ELTS;

  // ---------------- Phase 1 (merged): Q,K,V^T with one X load per mt -------
  {
    bh8 wq[4][2], wk[4][2], wvv[4][2];
    float bqf[4], bkf[4], bvf[4][4];
#pragma unroll
    for (int nt = 0; nt < 4; ++nt) {
      const int wrow = (16 * nt + l16) * 64 + 8 * q4;
      wq[nt][0]  = g_load8<FP32>(Wqv, wrow);
      wq[nt][1]  = g_load8<FP32>(Wqv, wrow + 32);
      wk[nt][0]  = g_load8<FP32>(Wkv, wrow);
      wk[nt][1]  = g_load8<FP32>(Wkv, wrow + 32);
      wvv[nt][0] = g_load8<FP32>(Wvv, wrow);
      wvv[nt][1] = g_load8<FP32>(Wvv, wrow + 32);
      bqf[nt]    = g_loadf<FP32>(bqv, 16 * nt + l16);
      bkf[nt]    = g_loadf<FP32>(bkv, 16 * nt + l16);
#pragma unroll
      for (int r = 0; r < 4; ++r)
        bvf[nt][r] = g_loadf<FP32>(bvv, 16 * nt + 4 * q4 + r);
    }
#pragma unroll
    for (int mt = 0; mt < 4; ++mt) {
      const size_t xr = xoff + (size_t)(m0w + 16 * mt + l16) * 64 + 8 * q4;
      bh8 xf0 = g_load8<FP32>(Xv, xr);
      bh8 xf1 = g_load8<FP32>(Xv, xr + 32);
      // Q projection -> sQ
#pragma unroll
      for (int nt = 0; nt < 4; ++nt) {
        f32x4 acc = {0.f, 0.f, 0.f, 0.f};
        acc = MFMA(xf0, wq[nt][0], acc);
        acc = MFMA(xf1, wq[nt][1], acc);
#pragma unroll
        for (int r = 0; r < 4; ++r)
          sQ[(m0w + 16 * mt + 4 * q4 + r) * SQ_STRIDE + 16 * nt + l16] =
              f2bf(acc[r] + bqf[nt]);
      }
      // K projection -> sK
#pragma unroll
      for (int nt = 0; nt < 4; ++nt) {
        f32x4 acc = {0.f, 0.f, 0.f, 0.f};
        acc = MFMA(xf0, wk[nt][0], acc);
        acc = MFMA(xf1, wk[nt][1], acc);
#pragma unroll
        for (int r = 0; r < 4; ++r)
          sK[(m0w + 16 * mt + 4 * q4 + r) * SQ_STRIDE + 16 * nt + l16] =
              f2bf(acc[r] + bkf[nt]);
      }
      // V^T projection -> sVt
#pragma unroll
      for (int dt = 0; dt < 4; ++dt) {
        f32x4 acc = {0.f, 0.f, 0.f, 0.f};
        acc = MFMA(wvv[dt][0], xf0, acc);
        acc = MFMA(wvv[dt][1], xf1, acc);
#pragma unroll
        for (int r = 0; r < 4; ++r)
          sVt[(16 * dt + 4 * q4 + r) * SVT_STRIDE + m0w + 16 * mt + l16] =
              f2bf(acc[r] + bvf[dt][r]);
      }
    }
  }
  __syncthreads();  // sQ/sK/sVt valid block-wide

  // Preload Wo fragments + output-stage constants once.
  bh8 wo[4][2];
  float bof[4], gf[4], lbf[4];
#pragma unroll
  for (int nt = 0; nt < 4; ++nt) {
    const int wrow = (16 * nt + l16) * 64 + 8 * q4;
    wo[nt][0] = g_load8<FP32>(Wov, wrow);
    wo[nt][1] = g_load8<FP32>(Wov, wrow + 32);
    const int col = 16 * nt + l16;
    bof[nt] = g_loadf<FP32>(bov, col);
    gf[nt]  = g_loadf<FP32>(lngv, col);
    lbf[nt] = g_loadf<FP32>(lnbv, col);
  }

  // Shuffle source lanes for the q4-axis fragment permutation (shared by
  // the P build and the ctx build):
  // target (q4,l16) dword j pulls from lane (2*(q4&1) + (j>>1), l16).
  const int srcA = ((lane & 16) << 1) | l16;  // q4' = 2*(q4&1)
  const int srcB = srcA + 16;                 // q4' = 2*(q4&1)+1
  const bool hsel = (lane & 32) != 0;         // h / dt-low selector = q4>>1

  // ---------------- Phase 2: fused S -> P -> PV -> out -> LN ----------------
#pragma unroll 1
  for (int mt = 0; mt < 4; ++mt) {
    const int a0 = m0w + 16 * mt;
    const unsigned short* krow = sK + (a0 + l16) * SQ_STRIDE + 8 * q4;
    bh8 kf0 = *(const bh8*)(krow);
    bh8 kf1 = *(const bh8*)(krow + 32);

    // Residual X loads hoisted: latency hides under the ct chain below.
    float xres[4][4];
#pragma unroll
    for (int nt = 0; nt < 4; ++nt)
#pragma unroll
      for (int r = 0; r < 4; ++r)
        xres[nt][r] = g_loadf<FP32>(
            Xv, xoff + (size_t)(a0 + 4 * q4 + r) * 64 + 16 * nt + l16);

    f32x4 ctxa[4];
#pragma unroll
    for (int dt = 0; dt < 4; ++dt) ctxa[dt] = (f32x4){0.f, 0.f, 0.f, 0.f};
    float rs = 0.f;  // row-sum for row a = a0+l16 (lane-local partial)

#pragma unroll 1
    for (int ct = 0; ct < 8; ++ct) {
      // Swapped QK^T: s[r] = S[c0+4*q4+r][a0+l16]
      int ph0[2], ph1[2];
#pragma unroll
      for (int h = 0; h < 2; ++h) {
        const int c0 = 32 * ct + 16 * h;
        const unsigned short* qrow = sQ + (c0 + l16) * SQ_STRIDE + 8 * q4;
        bh8 qf0 = *(const bh8*)(qrow);
        bh8 qf1 = *(const bh8*)(qrow + 32);
        f32x4 s = {0.f, 0.f, 0.f, 0.f};
        s = MFMA(qf0, kf0, s);
        s = MFMA(qf1, kf1, s);
        float v0 = fmaxf(s[0] * 0.125f, 0.f);
        float v1 = fmaxf(s[1] * 0.125f, 0.f);
        float v2 = fmaxf(s[2] * 0.125f, 0.f);
        float v3 = fmaxf(s[3] * 0.125f, 0.f);
        rs += (v0 + v1) + (v2 + v3);
        if (h == 0) { ph0[0] = pkbf(v0, v1); ph0[1] = pkbf(v2, v3); }
        else        { ph1[0] = pkbf(v0, v1); ph1[1] = pkbf(v2, v3); }
      }
      // Build PV B-fragment in-register (no LDS, no barrier).
      union { int d[4]; bh8 v; } pfu;
#pragma unroll
      for (int j = 0; j < 4; ++j) {
        const int srcl = (j < 2) ? srcA : srcB;
        int t0, t1;
        if ((j & 1) == 0) { t0 = __shfl(ph0[0], srcl); t1 = __shfl(ph1[0], srcl); }
        else              { t0 = __shfl(ph0[1], srcl); t1 = __shfl(ph1[1], srcl); }
        pfu.d[j] = hsel ? t1 : t0;
      }
#pragma unroll
      for (int dt = 0; dt < 4; ++dt) {
        bh8 vf = *(const bh8*)(sVt + (16 * dt + l16) * SVT_STRIDE + 32 * ct + 8 * q4);
        ctxa[dt] = MFMA(vf, pfu.v, ctxa[dt]);  // ctx^T[d][a]
      }
    }

    // denom = sum_c relu + M*1e-12 (reference adds 1e-12 inside the sum)
    rs += __shfl_xor(rs, 16);
    rs += __shfl_xor(rs, 32);
    const float inv = 1.f / (rs + 2.56e-10f);

    // ctx^T -> out-proj A-fragment IN-REGISTER (same permutation class as
    // the P build; replaces 16 ds_write + barrier + 2 ds_read_b128).
    // Source lane (q4',l16) holds ctx[l16][16dt+4q4'+r]; target (q4,l16)
    // needs d = 8q4+2j+e (+32 for cf1): dt = q4>>1 (+2), q4' = 2(q4&1)+(j>>1),
    // pack = j&1.
    int pc[4][2];
#pragma unroll
    for (int dt = 0; dt < 4; ++dt) {
      pc[dt][0] = pkbf(ctxa[dt][0] * inv, ctxa[dt][1] * inv);
      pc[dt][1] = pkbf(ctxa[dt][2] * inv, ctxa[dt][3] * inv);
    }
    union { int d[4]; bh8 v; } cf0u, cf1u;
#pragma unroll
    for (int j = 0; j < 4; ++j) {
      const int srcl = (j < 2) ? srcA : srcB;
      const int jp = j & 1;
      int t0 = __shfl(pc[0][jp], srcl);
      int t1 = __shfl(pc[1][jp], srcl);
      int t2 = __shfl(pc[2][jp], srcl);
      int t3 = __shfl(pc[3][jp], srcl);
      cf0u.d[j] = hsel ? t1 : t0;
      cf1u.d[j] = hsel ? t3 : t2;
    }

    float yv[4][4];
    float s1[4] = {0.f, 0.f, 0.f, 0.f};
    float s2[4] = {0.f, 0.f, 0.f, 0.f};
#pragma unroll
    for (int nt = 0; nt < 4; ++nt) {
      f32x4 o = {0.f, 0.f, 0.f, 0.f};
      o = MFMA(cf0u.v, wo[nt][0], o);
      o = MFMA(cf1u.v, wo[nt][1], o);
#pragma unroll
      for (int r = 0; r < 4; ++r) {
        float y = o[r] + bof[nt] + xres[nt][r];
        yv[nt][r] = y;
        s1[r] += y;
        s2[r] += y * y;
      }
    }
#pragma unroll
    for (int r = 0; r < 4; ++r) {
      s1[r] += __shfl_xor(s1[r], 1);
      s1[r] += __shfl_xor(s1[r], 2);
      s1[r] += __shfl_xor(s1[r], 4);
      s1[r] += __shfl_xor(s1[r], 8);
      s2[r] += __shfl_xor(s2[r], 1);
      s2[r] += __shfl_xor(s2[r], 2);
      s2[r] += __shfl_xor(s2[r], 4);
      s2[r] += __shfl_xor(s2[r], 8);
      const float mu   = s1[r] * 0.015625f;
      const float var  = s2[r] * 0.015625f - mu * mu;
      const float rstd = rsqrtf(var + 1e-5f);
      if constexpr (FP32) {
        float* Outf = (float*)Outv;
#pragma unroll
        for (int nt = 0; nt < 4; ++nt)
          Outf[xoff + (size_t)(a0 + 4 * q4 + r) * 64 + 16 * nt + l16] =
              (yv[nt][r] - mu) * rstd * gf[nt] + lbf[nt];
      } else {
#pragma unroll
        for (int nt = 0; nt < 4; ++nt)
          stg[(4 * q4 + r) * SY_STRIDE + 16 * nt + l16] =
              f2bf((yv[nt][r] - mu) * rstd * gf[nt] + lbf[nt]);
      }
    }
    if constexpr (!FP32) {
      __syncthreads();  // insurance: y stage write -> read
      const int row = lane >> 2, seg = lane & 3;
      const unsigned short* yr = stg + row * SY_STRIDE + seg * 8;
      uint4 u0 = *(const uint4*)(yr);
      uint4 u1 = *(const uint4*)(yr + 32);
      unsigned short* orow =
          (unsigned short*)Outv + xoff + (size_t)(a0 + row) * 64 + seg * 8;
      *(uint4*)(orow)      = u0;
      *(uint4*)(orow + 32) = u1;
    }
  }
}

extern "C" void kernel_launch(void* const* d_in, const int* in_sizes, int n_in,
                              void* d_out, int out_size, void* d_ws, size_t ws_size,
                              hipStream_t stream) {
  (void)n_in; (void)d_ws; (void)ws_size; (void)out_size;
  const void* X  = d_in[1];   // structure_matrix (d_in[0]=hidden_states unused)
  const void* Wq = d_in[2];  const void* bq = d_in[3];
  const void* Wk = d_in[4];  const void* bk = d_in[5];
  const void* Wv = d_in[6];  const void* bv = d_in[7];
  const void* Wo = d_in[8];  const void* bo = d_in[9];
  const void* lg = d_in[10]; const void* lb = d_in[11];

  // Host-side dtype dispatch: structure_matrix has 4*256*256*64 = 16777216
  // elements. If in_sizes[1] is a byte count it identifies the dtype and we
  // launch ONE kernel; any other value -> launch both (device sniff makes
  // the wrong one exit early, as before).
  const long long NELT = 16777216LL;
  const long long sz1  = (long long)in_sizes[1];
  bool want_bf16 = true, want_f32 = true;
  if (sz1 == NELT * 2) want_f32 = false;        // bf16 bytes
  else if (sz1 == NELT * 4) want_bf16 = false;  // fp32 bytes

  auto k0 = pairattn<0>;  // bf16 inputs/outputs
  auto k1 = pairattn<1>;  // fp32 inputs/outputs
  if (want_bf16) {
    hipFuncSetAttribute((const void*)k0, hipFuncAttributeMaxDynamicSharedMemorySize, LDS_BYTES);
    k0<<<1024, 256, LDS_BYTES, stream>>>(X, Wq, bq, Wk, bk, Wv, bv, Wo, bo, lg, lb, d_out);
  }
  if (want_f32) {
    hipFuncSetAttribute((const void*)k1, hipFuncAttributeMaxDynamicSharedMemorySize, LDS_BYTES);
    k1<<<1024, 256, LDS_BYTES, stream>>>(X, Wq, bq, Wk, bk, Wv, bv, Wo, bo, lg, lb, d_out);
  }
}

// Round 12
// 227.338 us; speedup vs baseline: 1.0389x; 1.0389x over previous
//
#include <hip/hip_runtime.h>

// ---------------------------------------------------------------------------
// SelfAttentionPairDim2: B=4, N=256, M=256, D=64. Output [4,256,256,64].
// PERSISTENT blocks: grid 256 (=CU count), each block processes 4 (b,i)
// tiles. Fused MFMA pipeline per tile:
//   QKV proj -> S=relu(K Q^T/8) -> rownorm -> P V -> out proj -> +x -> LN
//
// R12: block-turnover elimination. Ledger: R10 proved serial preload heads
// are the dominant overhead class (+14us metric from one hoist); at
// 1 block/CU (LDS-pinned) each CU ran 4 blocks SERIALLY, paying 4x
// {launch + 26-load weight preload + drain}. Persistent blocks load
// weights ONCE per CU and loop tiles: bi = blockIdx.x + 256*k, k=0..3.
// One trailing __syncthreads per tile protects sQ/sK/sVt WAR (FP32 mode
// has no other in-loop barriers). Per-tile dataflow is R11 verbatim.
// VGPR rises to ~300 (weights live across phase 2) -- cap is 512 at
// launch_bounds(256,1) and occupancy is LDS-pinned anyway.
// Ledger (what's dead): unroll2 (+27us), warmx (0), cache-warmth (0),
// ctx-LDS-removal (0, kept free). rocprof dur noise +-20%; trust metric.
// Frozen: 256 thr / 4 waves / 1 block/CU (any >1 wave/SIMD fails O(1),
// mechanism unknown -- R1/R2/R3/R5).
// ---------------------------------------------------------------------------

using bh8   = __attribute__((ext_vector_type(8))) short;
using f32x4 = __attribute__((ext_vector_type(4))) float;

#define MFMA(a, b, c) __builtin_amdgcn_mfma_f32_16x16x32_bf16((a), (b), (c), 0, 0, 0)

#define SQ_STRIDE  72   // elements; 144 B rows (16B aligned)
#define SVT_STRIDE 264  // elements; 528 B rows (16B aligned)
#define SY_STRIDE  72
#define STG_ELTS   (16 * 72)  // 1152 per wave (y staging only)
#define LDS_BYTES  ((256 * SQ_STRIDE * 2 + 64 * SVT_STRIDE + 4 * STG_ELTS) * 2)  // 116736 B

__device__ __forceinline__ float bf2f(unsigned short u) {
  union { unsigned int i; float f; } x;
  x.i = ((unsigned int)u) << 16;
  return x.f;
}
__device__ __forceinline__ unsigned short f2bf(float f) {
  union { float f; unsigned int i; } x;
  x.f = f;
  unsigned int u = x.i + 0x7FFFu + ((x.i >> 16) & 1u);  // RNE
  return (unsigned short)(u >> 16);
}
__device__ __forceinline__ int pkbf(float lo, float hi) {
  return (int)(((unsigned int)f2bf(hi) << 16) | (unsigned int)f2bf(lo));
}

template <int FP32>
__device__ __forceinline__ bh8 g_load8(const void* base, size_t idx) {
  if constexpr (FP32) {
    const float* p = (const float*)base + idx;
    float4 a = *(const float4*)p;
    float4 b = *(const float4*)(p + 4);
    bh8 r;
    r[0] = (short)f2bf(a.x); r[1] = (short)f2bf(a.y);
    r[2] = (short)f2bf(a.z); r[3] = (short)f2bf(a.w);
    r[4] = (short)f2bf(b.x); r[5] = (short)f2bf(b.y);
    r[6] = (short)f2bf(b.z); r[7] = (short)f2bf(b.w);
    return r;
  } else {
    return *(const bh8*)((const unsigned short*)base + idx);
  }
}
template <int FP32>
__device__ __forceinline__ float g_loadf(const void* base, size_t idx) {
  if constexpr (FP32) return ((const float*)base)[idx];
  else return bf2f(((const unsigned short*)base)[idx]);
}

template <int FP32>
__global__ __launch_bounds__(256, 1) void pairattn(
    const void* __restrict__ Xv,
    const void* __restrict__ Wqv, const void* __restrict__ bqv,
    const void* __restrict__ Wkv, const void* __restrict__ bkv,
    const void* __restrict__ Wvv, const void* __restrict__ bvv,
    const void* __restrict__ Wov, const void* __restrict__ bov,
    const void* __restrict__ lngv, const void* __restrict__ lnbv,
    void* __restrict__ Outv) {
  const int tid  = threadIdx.x;
  const int lane = tid & 63;

  // ---- dtype detection (block-uniform, deterministic; guard for the
  // dual-launch fallback path) ----
  {
    const unsigned short* xu = (const unsigned short*)Xv + (lane << 4);
    int huge = 0;
#pragma unroll
    for (int j = 0; j < 16; ++j) {
      unsigned e = ((unsigned)xu[j] >> 7) & 0xFFu;
      huge |= (e >= 0x90u) ? 1 : 0;
    }
    const bool isf32 = (__ballot(huge) != 0ULL);
    if (isf32 != (FP32 != 0)) return;  // uniform exit, before any barrier
  }

  extern __shared__ unsigned short sm[];
  unsigned short* sQ  = sm;                        // 256 x 72
  unsigned short* sK  = sQ + 256 * SQ_STRIDE;      // 256 x 72
  unsigned short* sVt = sK + 256 * SQ_STRIDE;      // 64 x 264 (V transposed)
  unsigned short* sSt = sVt + 64 * SVT_STRIDE;     // 4 x 1152 wave-private

  const int wv  = tid >> 6;
  const int q4  = lane >> 4;
  const int l16 = lane & 15;
  const int m0w = wv << 6;
  unsigned short* stg = sSt + wv * STG_ELTS;

  // ---- One-time preloads (amortized over 4 tiles; was per-block) ----------
  bh8 wq[4][2], wk[4][2], wvv[4][2], wo[4][2];
  float bqf[4], bkf[4], bvf[4][4], bof[4], gf[4], lbf[4];
#pragma unroll
  for (int nt = 0; nt < 4; ++nt) {
    const int wrow = (16 * nt + l16) * 64 + 8 * q4;
    wq[nt][0]  = g_load8<FP32>(Wqv, wrow);
    wq[nt][1]  = g_load8<FP32>(Wqv, wrow + 32);
    wk[nt][0]  = g_load8<FP32>(Wkv, wrow);
    wk[nt][1]  = g_load8<FP32>(Wkv, wrow + 32);
    wvv[nt][0] = g_load8<FP32>(Wvv, wrow);
    wvv[nt][1] = g_load8<FP32>(Wvv, wrow + 32);
    wo[nt][0]  = g_load8<FP32>(Wov, wrow);
    wo[nt][1]  = g_load8<FP32>(Wov, wrow + 32);
    const int col = 16 * nt + l16;
    bqf[nt] = g_loadf<FP32>(bqv, col);
    bkf[nt] = g_loadf<FP32>(bkv, col);
    bof[nt] = g_loadf<FP32>(bov, col);
    gf[nt]  = g_loadf<FP32>(lngv, col);
    lbf[nt] = g_loadf<FP32>(lnbv, col);
#pragma unroll
    for (int r = 0; r < 4; ++r)
      bvf[nt][r] = g_loadf<FP32>(bvv, 16 * nt + 4 * q4 + r);
  }

  // Shuffle source lanes for the q4-axis fragment permutation (shared by
  // the P build and the ctx build):
  // target (q4,l16) dword j pulls from lane (2*(q4&1) + (j>>1), l16).
  const int srcA = ((lane & 16) << 1) | l16;  // q4' = 2*(q4&1)
  const int srcB = srcA + 16;                 // q4' = 2*(q4&1)+1
  const bool hsel = (lane & 32) != 0;         // h / dt-low selector = q4>>1

  // =================== Persistent loop over 4 (b,i) tiles ==================
#pragma unroll 1
  for (int bi = blockIdx.x; bi < 1024; bi += 256) {
    const size_t xoff = (size_t)bi * 16384;

    // ---------------- Phase 1 (merged): Q,K,V^T, one X load per mt ---------
#pragma unroll
    for (int mt = 0; mt < 4; ++mt) {
      const size_t xr = xoff + (size_t)(m0w + 16 * mt + l16) * 64 + 8 * q4;
      bh8 xf0 = g_load8<FP32>(Xv, xr);
      bh8 xf1 = g_load8<FP32>(Xv, xr + 32);
      // Q projection -> sQ
#pragma unroll
      for (int nt = 0; nt < 4; ++nt) {
        f32x4 acc = {0.f, 0.f, 0.f, 0.f};
        acc = MFMA(xf0, wq[nt][0], acc);
        acc = MFMA(xf1, wq[nt][1], acc);
#pragma unroll
        for (int r = 0; r < 4; ++r)
          sQ[(m0w + 16 * mt + 4 * q4 + r) * SQ_STRIDE + 16 * nt + l16] =
              f2bf(acc[r] + bqf[nt]);
      }
      // K projection -> sK
#pragma unroll
      for (int nt = 0; nt < 4; ++nt) {
        f32x4 acc = {0.f, 0.f, 0.f, 0.f};
        acc = MFMA(xf0, wk[nt][0], acc);
        acc = MFMA(xf1, wk[nt][1], acc);
#pragma unroll
        for (int r = 0; r < 4; ++r)
          sK[(m0w + 16 * mt + 4 * q4 + r) * SQ_STRIDE + 16 * nt + l16] =
              f2bf(acc[r] + bkf[nt]);
      }
      // V^T projection -> sVt
#pragma unroll
      for (int dt = 0; dt < 4; ++dt) {
        f32x4 acc = {0.f, 0.f, 0.f, 0.f};
        acc = MFMA(wvv[dt][0], xf0, acc);
        acc = MFMA(wvv[dt][1], xf1, acc);
#pragma unroll
        for (int r = 0; r < 4; ++r)
          sVt[(16 * dt + 4 * q4 + r) * SVT_STRIDE + m0w + 16 * mt + l16] =
              f2bf(acc[r] + bvf[dt][r]);
      }
    }
    __syncthreads();  // sQ/sK/sVt valid block-wide

    // ---------------- Phase 2: fused S -> P -> PV -> out -> LN -------------
#pragma unroll 1
    for (int mt = 0; mt < 4; ++mt) {
      const int a0 = m0w + 16 * mt;
      const unsigned short* krow = sK + (a0 + l16) * SQ_STRIDE + 8 * q4;
      bh8 kf0 = *(const bh8*)(krow);
      bh8 kf1 = *(const bh8*)(krow + 32);

      // Residual X loads hoisted: latency hides under the ct chain below.
      float xres[4][4];
#pragma unroll
      for (int nt = 0; nt < 4; ++nt)
#pragma unroll
        for (int r = 0; r < 4; ++r)
          xres[nt][r] = g_loadf<FP32>(
              Xv, xoff + (size_t)(a0 + 4 * q4 + r) * 64 + 16 * nt + l16);

      f32x4 ctxa[4];
#pragma unroll
      for (int dt = 0; dt < 4; ++dt) ctxa[dt] = (f32x4){0.f, 0.f, 0.f, 0.f};
      float rs = 0.f;  // row-sum for row a = a0+l16 (lane-local partial)

#pragma unroll 1
      for (int ct = 0; ct < 8; ++ct) {
        // Swapped QK^T: s[r] = S[c0+4*q4+r][a0+l16]
        int ph0[2], ph1[2];
#pragma unroll
        for (int h = 0; h < 2; ++h) {
          const int c0 = 32 * ct + 16 * h;
          const unsigned short* qrow = sQ + (c0 + l16) * SQ_STRIDE + 8 * q4;
          bh8 qf0 = *(const bh8*)(qrow);
          bh8 qf1 = *(const bh8*)(qrow + 32);
          f32x4 s = {0.f, 0.f, 0.f, 0.f};
          s = MFMA(qf0, kf0, s);
          s = MFMA(qf1, kf1, s);
          float v0 = fmaxf(s[0] * 0.125f, 0.f);
          float v1 = fmaxf(s[1] * 0.125f, 0.f);
          float v2 = fmaxf(s[2] * 0.125f, 0.f);
          float v3 = fmaxf(s[3] * 0.125f, 0.f);
          rs += (v0 + v1) + (v2 + v3);
          if (h == 0) { ph0[0] = pkbf(v0, v1); ph0[1] = pkbf(v2, v3); }
          else        { ph1[0] = pkbf(v0, v1); ph1[1] = pkbf(v2, v3); }
        }
        // Build PV B-fragment in-register (no LDS, no barrier).
        union { int d[4]; bh8 v; } pfu;
#pragma unroll
        for (int j = 0; j < 4; ++j) {
          const int srcl = (j < 2) ? srcA : srcB;
          int t0, t1;
          if ((j & 1) == 0) { t0 = __shfl(ph0[0], srcl); t1 = __shfl(ph1[0], srcl); }
          else              { t0 = __shfl(ph0[1], srcl); t1 = __shfl(ph1[1], srcl); }
          pfu.d[j] = hsel ? t1 : t0;
        }
#pragma unroll
        for (int dt = 0; dt < 4; ++dt) {
          bh8 vf = *(const bh8*)(sVt + (16 * dt + l16) * SVT_STRIDE + 32 * ct + 8 * q4);
          ctxa[dt] = MFMA(vf, pfu.v, ctxa[dt]);  // ctx^T[d][a]
        }
      }

      // denom = sum_c relu + M*1e-12 (reference adds 1e-12 inside the sum)
      rs += __shfl_xor(rs, 16);
      rs += __shfl_xor(rs, 32);
      const float inv = 1.f / (rs + 2.56e-10f);

      // ctx^T -> out-proj A-fragment IN-REGISTER (same permutation class as
      // the P build). dt = q4>>1 (+2 for cf1), q4' = 2(q4&1)+(j>>1), pack=j&1.
      int pc[4][2];
#pragma unroll
      for (int dt = 0; dt < 4; ++dt) {
        pc[dt][0] = pkbf(ctxa[dt][0] * inv, ctxa[dt][1] * inv);
        pc[dt][1] = pkbf(ctxa[dt][2] * inv, ctxa[dt][3] * inv);
      }
      union { int d[4]; bh8 v; } cf0u, cf1u;
#pragma unroll
      for (int j = 0; j < 4; ++j) {
        const int srcl = (j < 2) ? srcA : srcB;
        const int jp = j & 1;
        int t0 = __shfl(pc[0][jp], srcl);
        int t1 = __shfl(pc[1][jp], srcl);
        int t2 = __shfl(pc[2][jp], srcl);
        int t3 = __shfl(pc[3][jp], srcl);
        cf0u.d[j] = hsel ? t1 : t0;
        cf1u.d[j] = hsel ? t3 : t2;
      }

      float yv[4][4];
      float s1[4] = {0.f, 0.f, 0.f, 0.f};
      float s2[4] = {0.f, 0.f, 0.f, 0.f};
#pragma unroll
      for (int nt = 0; nt < 4; ++nt) {
        f32x4 o = {0.f, 0.f, 0.f, 0.f};
        o = MFMA(cf0u.v, wo[nt][0], o);
        o = MFMA(cf1u.v, wo[nt][1], o);
#pragma unroll
        for (int r = 0; r < 4; ++r) {
          float y = o[r] + bof[nt] + xres[nt][r];
          yv[nt][r] = y;
          s1[r] += y;
          s2[r] += y * y;
        }
      }
#pragma unroll
      for (int r = 0; r < 4; ++r) {
        s1[r] += __shfl_xor(s1[r], 1);
        s1[r] += __shfl_xor(s1[r], 2);
        s1[r] += __shfl_xor(s1[r], 4);
        s1[r] += __shfl_xor(s1[r], 8);
        s2[r] += __shfl_xor(s2[r], 1);
        s2[r] += __shfl_xor(s2[r], 2);
        s2[r] += __shfl_xor(s2[r], 4);
        s2[r] += __shfl_xor(s2[r], 8);
        const float mu   = s1[r] * 0.015625f;
        const float var  = s2[r] * 0.015625f - mu * mu;
        const float rstd = rsqrtf(var + 1e-5f);
        if constexpr (FP32) {
          float* Outf = (float*)Outv;
#pragma unroll
          for (int nt = 0; nt < 4; ++nt)
            Outf[xoff + (size_t)(a0 + 4 * q4 + r) * 64 + 16 * nt + l16] =
                (yv[nt][r] - mu) * rstd * gf[nt] + lbf[nt];
        } else {
#pragma unroll
          for (int nt = 0; nt < 4; ++nt)
            stg[(4 * q4 + r) * SY_STRIDE + 16 * nt + l16] =
                f2bf((yv[nt][r] - mu) * rstd * gf[nt] + lbf[nt]);
        }
      }
      if constexpr (!FP32) {
        __syncthreads();  // insurance: y stage write -> read
        const int row = lane >> 2, seg = lane & 3;
        const unsigned short* yr = stg + row * SY_STRIDE + seg * 8;
        uint4 u0 = *(const uint4*)(yr);
        uint4 u1 = *(const uint4*)(yr + 32);
        unsigned short* orow =
            (unsigned short*)Outv + xoff + (size_t)(a0 + row) * 64 + seg * 8;
        *(uint4*)(orow)      = u0;
        *(uint4*)(orow + 32) = u1;
      }
    }
    __syncthreads();  // end-of-tile: protect sQ/sK/sVt WAR for next bi
  }
}

extern "C" void kernel_launch(void* const* d_in, const int* in_sizes, int n_in,
                              void* d_out, int out_size, void* d_ws, size_t ws_size,
                              hipStream_t stream) {
  (void)n_in; (void)d_ws; (void)ws_size; (void)out_size;
  const void* X  = d_in[1];   // structure_matrix (d_in[0]=hidden_states unused)
  const void* Wq = d_in[2];  const void* bq = d_in[3];
  const void* Wk = d_in[4];  const void* bk = d_in[5];
  const void* Wv = d_in[6];  const void* bv = d_in[7];
  const void* Wo = d_in[8];  const void* bo = d_in[9];
  const void* lg = d_in[10]; const void* lb = d_in[11];

  // Host-side dtype dispatch: structure_matrix has 4*256*256*64 = 16777216
  // elements. If in_sizes[1] is a byte count it identifies the dtype and we
  // launch ONE kernel; any other value -> launch both (device sniff makes
  // the wrong one exit early, as before).
  const long long NELT = 16777216LL;
  const long long sz1  = (long long)in_sizes[1];
  bool want_bf16 = true, want_f32 = true;
  if (sz1 == NELT * 2) want_f32 = false;        // bf16 bytes
  else if (sz1 == NELT * 4) want_bf16 = false;  // fp32 bytes

  auto k0 = pairattn<0>;  // bf16 inputs/outputs
  auto k1 = pairattn<1>;  // fp32 inputs/outputs
  if (want_bf16) {
    hipFuncSetAttribute((const void*)k0, hipFuncAttributeMaxDynamicSharedMemorySize, LDS_BYTES);
    k0<<<256, 256, LDS_BYTES, stream>>>(X, Wq, bq, Wk, bk, Wv, bv, Wo, bo, lg, lb, d_out);
  }
  if (want_f32) {
    hipFuncSetAttribute((const void*)k1, hipFuncAttributeMaxDynamicSharedMemorySize, LDS_BYTES);
    k1<<<256, 256, LDS_BYTES, stream>>>(X, Wq, bq, Wk, bk, Wv, bv, Wo, bo, lg, lb, d_out);
  }
}

// Round 13
// 227.049 us; speedup vs baseline: 1.0402x; 1.0013x over previous
//
#include <hip/hip_runtime.h>

// ---------------------------------------------------------------------------
// SelfAttentionPairDim2: B=4, N=256, M=256, D=64. Output [4,256,256,64].
// PERSISTENT blocks: grid 256 (=CU count), each block processes 4 (b,i)
// tiles. Fused MFMA pipeline per tile:
//   QKV proj -> S=relu(K Q^T/8) -> rownorm -> P V -> out proj -> +x -> LN
//
// R13: ledger correction + two verified-class levers on R12:
//  * Metric is the trusted signal (R8 248.38 vs R9 248.34 identical-binary;
//    hot-dispatch noise +-20%, R8 147 vs R9 180). By metric, R7's ct-loop
//    unroll-2 was a -8us WIN (240 vs 248), misattributed as a regression
//    from a noisy hot reading. REINSTATED here (barrier-free loop; 2x ILP).
//  * Phase-1 X prefetch: all 4 mt x-tiles loaded up front (+32 VGPR), one
//    global-latency exposure per tile instead of 4 (R10/R11 reorder class).
// R12 kept: persistent blocks (weights loaded once per CU, 4-tile loop),
// merged phase 1, all weights/biases/Wo preloaded, swapped QK^T,
// in-register P and ctx fragments, single-dispatch host path.
// Frozen: 256 thr / 4 waves / 1 block/CU (any >1 wave/SIMD fails O(1),
// mechanism unknown -- R1/R2/R3/R5).
// ---------------------------------------------------------------------------

using bh8   = __attribute__((ext_vector_type(8))) short;
using f32x4 = __attribute__((ext_vector_type(4))) float;

#define MFMA(a, b, c) __builtin_amdgcn_mfma_f32_16x16x32_bf16((a), (b), (c), 0, 0, 0)

#define SQ_STRIDE  72   // elements; 144 B rows (16B aligned)
#define SVT_STRIDE 264  // elements; 528 B rows (16B aligned)
#define SY_STRIDE  72
#define STG_ELTS   (16 * 72)  // 1152 per wave (y staging only)
#define LDS_BYTES  ((256 * SQ_STRIDE * 2 + 64 * SVT_STRIDE + 4 * STG_ELTS) * 2)  // 116736 B

__device__ __forceinline__ float bf2f(unsigned short u) {
  union { unsigned int i; float f; } x;
  x.i = ((unsigned int)u) << 16;
  return x.f;
}
__device__ __forceinline__ unsigned short f2bf(float f) {
  union { float f; unsigned int i; } x;
  x.f = f;
  unsigned int u = x.i + 0x7FFFu + ((x.i >> 16) & 1u);  // RNE
  return (unsigned short)(u >> 16);
}
__device__ __forceinline__ int pkbf(float lo, float hi) {
  return (int)(((unsigned int)f2bf(hi) << 16) | (unsigned int)f2bf(lo));
}

template <int FP32>
__device__ __forceinline__ bh8 g_load8(const void* base, size_t idx) {
  if constexpr (FP32) {
    const float* p = (const float*)base + idx;
    float4 a = *(const float4*)p;
    float4 b = *(const float4*)(p + 4);
    bh8 r;
    r[0] = (short)f2bf(a.x); r[1] = (short)f2bf(a.y);
    r[2] = (short)f2bf(a.z); r[3] = (short)f2bf(a.w);
    r[4] = (short)f2bf(b.x); r[5] = (short)f2bf(b.y);
    r[6] = (short)f2bf(b.z); r[7] = (short)f2bf(b.w);
    return r;
  } else {
    return *(const bh8*)((const unsigned short*)base + idx);
  }
}
template <int FP32>
__device__ __forceinline__ float g_loadf(const void* base, size_t idx) {
  if constexpr (FP32) return ((const float*)base)[idx];
  else return bf2f(((const unsigned short*)base)[idx]);
}

template <int FP32>
__global__ __launch_bounds__(256, 1) void pairattn(
    const void* __restrict__ Xv,
    const void* __restrict__ Wqv, const void* __restrict__ bqv,
    const void* __restrict__ Wkv, const void* __restrict__ bkv,
    const void* __restrict__ Wvv, const void* __restrict__ bvv,
    const void* __restrict__ Wov, const void* __restrict__ bov,
    const void* __restrict__ lngv, const void* __restrict__ lnbv,
    void* __restrict__ Outv) {
  const int tid  = threadIdx.x;
  const int lane = tid & 63;

  // ---- dtype detection (block-uniform, deterministic; guard for the
  // dual-launch fallback path) ----
  {
    const unsigned short* xu = (const unsigned short*)Xv + (lane << 4);
    int huge = 0;
#pragma unroll
    for (int j = 0; j < 16; ++j) {
      unsigned e = ((unsigned)xu[j] >> 7) & 0xFFu;
      huge |= (e >= 0x90u) ? 1 : 0;
    }
    const bool isf32 = (__ballot(huge) != 0ULL);
    if (isf32 != (FP32 != 0)) return;  // uniform exit, before any barrier
  }

  extern __shared__ unsigned short sm[];
  unsigned short* sQ  = sm;                        // 256 x 72
  unsigned short* sK  = sQ + 256 * SQ_STRIDE;      // 256 x 72
  unsigned short* sVt = sK + 256 * SQ_STRIDE;      // 64 x 264 (V transposed)
  unsigned short* sSt = sVt + 64 * SVT_STRIDE;     // 4 x 1152 wave-private

  const int wv  = tid >> 6;
  const int q4  = lane >> 4;
  const int l16 = lane & 15;
  const int m0w = wv << 6;
  unsigned short* stg = sSt + wv * STG_ELTS;

  // ---- One-time preloads (amortized over 4 tiles) -------------------------
  bh8 wq[4][2], wk[4][2], wvv[4][2], wo[4][2];
  float bqf[4], bkf[4], bvf[4][4], bof[4], gf[4], lbf[4];
#pragma unroll
  for (int nt = 0; nt < 4; ++nt) {
    const int wrow = (16 * nt + l16) * 64 + 8 * q4;
    wq[nt][0]  = g_load8<FP32>(Wqv, wrow);
    wq[nt][1]  = g_load8<FP32>(Wqv, wrow + 32);
    wk[nt][0]  = g_load8<FP32>(Wkv, wrow);
    wk[nt][1]  = g_load8<FP32>(Wkv, wrow + 32);
    wvv[nt][0] = g_load8<FP32>(Wvv, wrow);
    wvv[nt][1] = g_load8<FP32>(Wvv, wrow + 32);
    wo[nt][0]  = g_load8<FP32>(Wov, wrow);
    wo[nt][1]  = g_load8<FP32>(Wov, wrow + 32);
    const int col = 16 * nt + l16;
    bqf[nt] = g_loadf<FP32>(bqv, col);
    bkf[nt] = g_loadf<FP32>(bkv, col);
    bof[nt] = g_loadf<FP32>(bov, col);
    gf[nt]  = g_loadf<FP32>(lngv, col);
    lbf[nt] = g_loadf<FP32>(lnbv, col);
#pragma unroll
    for (int r = 0; r < 4; ++r)
      bvf[nt][r] = g_loadf<FP32>(bvv, 16 * nt + 4 * q4 + r);
  }

  // Shuffle source lanes for the q4-axis fragment permutation (shared by
  // the P build and the ctx build):
  // target (q4,l16) dword j pulls from lane (2*(q4&1) + (j>>1), l16).
  const int srcA = ((lane & 16) << 1) | l16;  // q4' = 2*(q4&1)
  const int srcB = srcA + 16;                 // q4' = 2*(q4&1)+1
  const bool hsel = (lane & 32) != 0;         // h / dt-low selector = q4>>1

  // =================== Persistent loop over 4 (b,i) tiles ==================
#pragma unroll 1
  for (int bi = blockIdx.x; bi < 1024; bi += 256) {
    const size_t xoff = (size_t)bi * 16384;

    // ---------------- Phase 1 (merged): Q,K,V^T ----------------------------
    // X prefetch: all 4 mt tiles issued up front (one latency exposure).
    {
      bh8 xf[4][2];
#pragma unroll
      for (int mt = 0; mt < 4; ++mt) {
        const size_t xr = xoff + (size_t)(m0w + 16 * mt + l16) * 64 + 8 * q4;
        xf[mt][0] = g_load8<FP32>(Xv, xr);
        xf[mt][1] = g_load8<FP32>(Xv, xr + 32);
      }
#pragma unroll
      for (int mt = 0; mt < 4; ++mt) {
        // Q projection -> sQ
#pragma unroll
        for (int nt = 0; nt < 4; ++nt) {
          f32x4 acc = {0.f, 0.f, 0.f, 0.f};
          acc = MFMA(xf[mt][0], wq[nt][0], acc);
          acc = MFMA(xf[mt][1], wq[nt][1], acc);
#pragma unroll
          for (int r = 0; r < 4; ++r)
            sQ[(m0w + 16 * mt + 4 * q4 + r) * SQ_STRIDE + 16 * nt + l16] =
                f2bf(acc[r] + bqf[nt]);
        }
        // K projection -> sK
#pragma unroll
        for (int nt = 0; nt < 4; ++nt) {
          f32x4 acc = {0.f, 0.f, 0.f, 0.f};
          acc = MFMA(xf[mt][0], wk[nt][0], acc);
          acc = MFMA(xf[mt][1], wk[nt][1], acc);
#pragma unroll
          for (int r = 0; r < 4; ++r)
            sK[(m0w + 16 * mt + 4 * q4 + r) * SQ_STRIDE + 16 * nt + l16] =
                f2bf(acc[r] + bkf[nt]);
        }
        // V^T projection -> sVt
#pragma unroll
        for (int dt = 0; dt < 4; ++dt) {
          f32x4 acc = {0.f, 0.f, 0.f, 0.f};
          acc = MFMA(wvv[dt][0], xf[mt][0], acc);
          acc = MFMA(wvv[dt][1], xf[mt][1], acc);
#pragma unroll
          for (int r = 0; r < 4; ++r)
            sVt[(16 * dt + 4 * q4 + r) * SVT_STRIDE + m0w + 16 * mt + l16] =
                f2bf(acc[r] + bvf[dt][r]);
        }
      }
    }
    __syncthreads();  // sQ/sK/sVt valid block-wide

    // ---------------- Phase 2: fused S -> P -> PV -> out -> LN -------------
#pragma unroll 1
    for (int mt = 0; mt < 4; ++mt) {
      const int a0 = m0w + 16 * mt;
      const unsigned short* krow = sK + (a0 + l16) * SQ_STRIDE + 8 * q4;
      bh8 kf0 = *(const bh8*)(krow);
      bh8 kf1 = *(const bh8*)(krow + 32);

      // Residual X loads hoisted: latency hides under the ct chain below.
      float xres[4][4];
#pragma unroll
      for (int nt = 0; nt < 4; ++nt)
#pragma unroll
        for (int r = 0; r < 4; ++r)
          xres[nt][r] = g_loadf<FP32>(
              Xv, xoff + (size_t)(a0 + 4 * q4 + r) * 64 + 16 * nt + l16);

      f32x4 ctxa[4];
#pragma unroll
      for (int dt = 0; dt < 4; ++dt) ctxa[dt] = (f32x4){0.f, 0.f, 0.f, 0.f};
      float rs = 0.f;  // row-sum for row a = a0+l16 (lane-local partial)

      // Barrier-free loop; unroll 2 interleaves two iterations' ds_reads/
      // MFMAs/shuffles (metric-verified +8us: R7 240 vs R9 248).
#pragma unroll 2
      for (int ct = 0; ct < 8; ++ct) {
        // Swapped QK^T: s[r] = S[c0+4*q4+r][a0+l16]
        int ph0[2], ph1[2];
#pragma unroll
        for (int h = 0; h < 2; ++h) {
          const int c0 = 32 * ct + 16 * h;
          const unsigned short* qrow = sQ + (c0 + l16) * SQ_STRIDE + 8 * q4;
          bh8 qf0 = *(const bh8*)(qrow);
          bh8 qf1 = *(const bh8*)(qrow + 32);
          f32x4 s = {0.f, 0.f, 0.f, 0.f};
          s = MFMA(qf0, kf0, s);
          s = MFMA(qf1, kf1, s);
          float v0 = fmaxf(s[0] * 0.125f, 0.f);
          float v1 = fmaxf(s[1] * 0.125f, 0.f);
          float v2 = fmaxf(s[2] * 0.125f, 0.f);
          float v3 = fmaxf(s[3] * 0.125f, 0.f);
          rs += (v0 + v1) + (v2 + v3);
          if (h == 0) { ph0[0] = pkbf(v0, v1); ph0[1] = pkbf(v2, v3); }
          else        { ph1[0] = pkbf(v0, v1); ph1[1] = pkbf(v2, v3); }
        }
        // Build PV B-fragment in-register (no LDS, no barrier).
        union { int d[4]; bh8 v; } pfu;
#pragma unroll
        for (int j = 0; j < 4; ++j) {
          const int srcl = (j < 2) ? srcA : srcB;
          int t0, t1;
          if ((j & 1) == 0) { t0 = __shfl(ph0[0], srcl); t1 = __shfl(ph1[0], srcl); }
          else              { t0 = __shfl(ph0[1], srcl); t1 = __shfl(ph1[1], srcl); }
          pfu.d[j] = hsel ? t1 : t0;
        }
#pragma unroll
        for (int dt = 0; dt < 4; ++dt) {
          bh8 vf = *(const bh8*)(sVt + (16 * dt + l16) * SVT_STRIDE + 32 * ct + 8 * q4);
          ctxa[dt] = MFMA(vf, pfu.v, ctxa[dt]);  // ctx^T[d][a]
        }
      }

      // denom = sum_c relu + M*1e-12 (reference adds 1e-12 inside the sum)
      rs += __shfl_xor(rs, 16);
      rs += __shfl_xor(rs, 32);
      const float inv = 1.f / (rs + 2.56e-10f);

      // ctx^T -> out-proj A-fragment IN-REGISTER (same permutation class as
      // the P build). dt = q4>>1 (+2 for cf1), q4' = 2(q4&1)+(j>>1), pack=j&1.
      int pc[4][2];
#pragma unroll
      for (int dt = 0; dt < 4; ++dt) {
        pc[dt][0] = pkbf(ctxa[dt][0] * inv, ctxa[dt][1] * inv);
        pc[dt][1] = pkbf(ctxa[dt][2] * inv, ctxa[dt][3] * inv);
      }
      union { int d[4]; bh8 v; } cf0u, cf1u;
#pragma unroll
      for (int j = 0; j < 4; ++j) {
        const int srcl = (j < 2) ? srcA : srcB;
        const int jp = j & 1;
        int t0 = __shfl(pc[0][jp], srcl);
        int t1 = __shfl(pc[1][jp], srcl);
        int t2 = __shfl(pc[2][jp], srcl);
        int t3 = __shfl(pc[3][jp], srcl);
        cf0u.d[j] = hsel ? t1 : t0;
        cf1u.d[j] = hsel ? t3 : t2;
      }

      float yv[4][4];
      float s1[4] = {0.f, 0.f, 0.f, 0.f};
      float s2[4] = {0.f, 0.f, 0.f, 0.f};
#pragma unroll
      for (int nt = 0; nt < 4; ++nt) {
        f32x4 o = {0.f, 0.f, 0.f, 0.f};
        o = MFMA(cf0u.v, wo[nt][0], o);
        o = MFMA(cf1u.v, wo[nt][1], o);
#pragma unroll
        for (int r = 0; r < 4; ++r) {
          float y = o[r] + bof[nt] + xres[nt][r];
          yv[nt][r] = y;
          s1[r] += y;
          s2[r] += y * y;
        }
      }
#pragma unroll
      for (int r = 0; r < 4; ++r) {
        s1[r] += __shfl_xor(s1[r], 1);
        s1[r] += __shfl_xor(s1[r], 2);
        s1[r] += __shfl_xor(s1[r], 4);
        s1[r] += __shfl_xor(s1[r], 8);
        s2[r] += __shfl_xor(s2[r], 1);
        s2[r] += __shfl_xor(s2[r], 2);
        s2[r] += __shfl_xor(s2[r], 4);
        s2[r] += __shfl_xor(s2[r], 8);
        const float mu   = s1[r] * 0.015625f;
        const float var  = s2[r] * 0.015625f - mu * mu;
        const float rstd = rsqrtf(var + 1e-5f);
        if constexpr (FP32) {
          float* Outf = (float*)Outv;
#pragma unroll
          for (int nt = 0; nt < 4; ++nt)
            Outf[xoff + (size_t)(a0 + 4 * q4 + r) * 64 + 16 * nt + l16] =
                (yv[nt][r] - mu) * rstd * gf[nt] + lbf[nt];
        } else {
#pragma unroll
          for (int nt = 0; nt < 4; ++nt)
            stg[(4 * q4 + r) * SY_STRIDE + 16 * nt + l16] =
                f2bf((yv[nt][r] - mu) * rstd * gf[nt] + lbf[nt]);
        }
      }
      if constexpr (!FP32) {
        __syncthreads();  // insurance: y stage write -> read
        const int row = lane >> 2, seg = lane & 3;
        const unsigned short* yr = stg + row * SY_STRIDE + seg * 8;
        uint4 u0 = *(const uint4*)(yr);
        uint4 u1 = *(const uint4*)(yr + 32);
        unsigned short* orow =
            (unsigned short*)Outv + xoff + (size_t)(a0 + row) * 64 + seg * 8;
        *(uint4*)(orow)      = u0;
        *(uint4*)(orow + 32) = u1;
      }
    }
    __syncthreads();  // end-of-tile: protect sQ/sK/sVt WAR for next bi
  }
}

extern "C" void kernel_launch(void* const* d_in, const int* in_sizes, int n_in,
                              void* d_out, int out_size, void* d_ws, size_t ws_size,
                              hipStream_t stream) {
  (void)n_in; (void)d_ws; (void)ws_size; (void)out_size;
  const void* X  = d_in[1];   // structure_matrix (d_in[0]=hidden_states unused)
  const void* Wq = d_in[2];  const void* bq = d_in[3];
  const void* Wk = d_in[4];  const void* bk = d_in[5];
  const void* Wv = d_in[6];  const void* bv = d_in[7];
  const void* Wo = d_in[8];  const void* bo = d_in[9];
  const void* lg = d_in[10]; const void* lb = d_in[11];

  // Host-side dtype dispatch: structure_matrix has 4*256*256*64 = 16777216
  // elements. If in_sizes[1] is a byte count it identifies the dtype and we
  // launch ONE kernel; any other value -> launch both (device sniff makes
  // the wrong one exit early, as before).
  const long long NELT = 16777216LL;
  const long long sz1  = (long long)in_sizes[1];
  bool want_bf16 = true, want_f32 = true;
  if (sz1 == NELT * 2) want_f32 = false;        // bf16 bytes
  else if (sz1 == NELT * 4) want_bf16 = false;  // fp32 bytes

  auto k0 = pairattn<0>;  // bf16 inputs/outputs
  auto k1 = pairattn<1>;  // fp32 inputs/outputs
  if (want_bf16) {
    hipFuncSetAttribute((const void*)k0, hipFuncAttributeMaxDynamicSharedMemorySize, LDS_BYTES);
    k0<<<256, 256, LDS_BYTES, stream>>>(X, Wq, bq, Wk, bk, Wv, bv, Wo, bo, lg, lb, d_out);
  }
  if (want_f32) {
    hipFuncSetAttribute((const void*)k1, hipFuncAttributeMaxDynamicSharedMemorySize, LDS_BYTES);
    k1<<<256, 256, LDS_BYTES, stream>>>(X, Wq, bq, Wk, bk, Wv, bv, Wo, bo, lg, lb, d_out);
  }
}

// Round 14
// 219.589 us; speedup vs baseline: 1.0756x; 1.0340x over previous
//
#include <hip/hip_runtime.h>

// ---------------------------------------------------------------------------
// SelfAttentionPairDim2: B=4, N=256, M=256, D=64. Output [4,256,256,64].
// PERSISTENT blocks: grid 256 (=CU count), each block processes 4 (b,i)
// tiles. Fused MFMA pipeline per tile:
//   QKV proj -> S=relu(K Q^T/8) -> rownorm -> P V -> out proj -> +x -> LN
//
// R14: V-fragment hoist. Phase-2's vf reads depend only on (dt,ct) -- they
// were re-issued identically in every mt iteration (128 ds_read_b128 per
// tile per wave where 32 suffice), contending on the shared LDS pipe
// (4 waves x 1 unit) and sitting on the PV dependency chain. Hoisted to
// vfr[8][4] registers once per tile (+128 VGPR, ~290 total, cap 512 at
// 1 block/CU). ct loop FULLY unrolled so vfr indexing is static (rule:
// runtime-indexed reg arrays spill to scratch).
// Ledger: preload/amortize class done (R6/R10/R12 wins, R11/R13 neutral);
// unroll-2 neutral on persistent structure; warmx/cache-warmth dead;
// rocprof hot-dispatch noise +-20% -- trust the bench metric.
// Frozen: 256 thr / 4 waves / 1 block/CU (any >1 wave/SIMD fails O(1),
// mechanism unknown -- R1/R2/R3/R5).
// ---------------------------------------------------------------------------

using bh8   = __attribute__((ext_vector_type(8))) short;
using f32x4 = __attribute__((ext_vector_type(4))) float;

#define MFMA(a, b, c) __builtin_amdgcn_mfma_f32_16x16x32_bf16((a), (b), (c), 0, 0, 0)

#define SQ_STRIDE  72   // elements; 144 B rows (16B aligned)
#define SVT_STRIDE 264  // elements; 528 B rows (16B aligned)
#define SY_STRIDE  72
#define STG_ELTS   (16 * 72)  // 1152 per wave (y staging only)
#define LDS_BYTES  ((256 * SQ_STRIDE * 2 + 64 * SVT_STRIDE + 4 * STG_ELTS) * 2)  // 116736 B

__device__ __forceinline__ float bf2f(unsigned short u) {
  union { unsigned int i; float f; } x;
  x.i = ((unsigned int)u) << 16;
  return x.f;
}
__device__ __forceinline__ unsigned short f2bf(float f) {
  union { float f; unsigned int i; } x;
  x.f = f;
  unsigned int u = x.i + 0x7FFFu + ((x.i >> 16) & 1u);  // RNE
  return (unsigned short)(u >> 16);
}
__device__ __forceinline__ int pkbf(float lo, float hi) {
  return (int)(((unsigned int)f2bf(hi) << 16) | (unsigned int)f2bf(lo));
}

template <int FP32>
__device__ __forceinline__ bh8 g_load8(const void* base, size_t idx) {
  if constexpr (FP32) {
    const float* p = (const float*)base + idx;
    float4 a = *(const float4*)p;
    float4 b = *(const float4*)(p + 4);
    bh8 r;
    r[0] = (short)f2bf(a.x); r[1] = (short)f2bf(a.y);
    r[2] = (short)f2bf(a.z); r[3] = (short)f2bf(a.w);
    r[4] = (short)f2bf(b.x); r[5] = (short)f2bf(b.y);
    r[6] = (short)f2bf(b.z); r[7] = (short)f2bf(b.w);
    return r;
  } else {
    return *(const bh8*)((const unsigned short*)base + idx);
  }
}
template <int FP32>
__device__ __forceinline__ float g_loadf(const void* base, size_t idx) {
  if constexpr (FP32) return ((const float*)base)[idx];
  else return bf2f(((const unsigned short*)base)[idx]);
}

template <int FP32>
__global__ __launch_bounds__(256, 1) void pairattn(
    const void* __restrict__ Xv,
    const void* __restrict__ Wqv, const void* __restrict__ bqv,
    const void* __restrict__ Wkv, const void* __restrict__ bkv,
    const void* __restrict__ Wvv, const void* __restrict__ bvv,
    const void* __restrict__ Wov, const void* __restrict__ bov,
    const void* __restrict__ lngv, const void* __restrict__ lnbv,
    void* __restrict__ Outv) {
  const int tid  = threadIdx.x;
  const int lane = tid & 63;

  // ---- dtype detection (block-uniform, deterministic; guard for the
  // dual-launch fallback path) ----
  {
    const unsigned short* xu = (const unsigned short*)Xv + (lane << 4);
    int huge = 0;
#pragma unroll
    for (int j = 0; j < 16; ++j) {
      unsigned e = ((unsigned)xu[j] >> 7) & 0xFFu;
      huge |= (e >= 0x90u) ? 1 : 0;
    }
    const bool isf32 = (__ballot(huge) != 0ULL);
    if (isf32 != (FP32 != 0)) return;  // uniform exit, before any barrier
  }

  extern __shared__ unsigned short sm[];
  unsigned short* sQ  = sm;                        // 256 x 72
  unsigned short* sK  = sQ + 256 * SQ_STRIDE;      // 256 x 72
  unsigned short* sVt = sK + 256 * SQ_STRIDE;      // 64 x 264 (V transposed)
  unsigned short* sSt = sVt + 64 * SVT_STRIDE;     // 4 x 1152 wave-private

  const int wv  = tid >> 6;
  const int q4  = lane >> 4;
  const int l16 = lane & 15;
  const int m0w = wv << 6;
  unsigned short* stg = sSt + wv * STG_ELTS;

  // ---- One-time preloads (amortized over 4 tiles) -------------------------
  bh8 wq[4][2], wk[4][2], wvv[4][2], wo[4][2];
  float bqf[4], bkf[4], bvf[4][4], bof[4], gf[4], lbf[4];
#pragma unroll
  for (int nt = 0; nt < 4; ++nt) {
    const int wrow = (16 * nt + l16) * 64 + 8 * q4;
    wq[nt][0]  = g_load8<FP32>(Wqv, wrow);
    wq[nt][1]  = g_load8<FP32>(Wqv, wrow + 32);
    wk[nt][0]  = g_load8<FP32>(Wkv, wrow);
    wk[nt][1]  = g_load8<FP32>(Wkv, wrow + 32);
    wvv[nt][0] = g_load8<FP32>(Wvv, wrow);
    wvv[nt][1] = g_load8<FP32>(Wvv, wrow + 32);
    wo[nt][0]  = g_load8<FP32>(Wov, wrow);
    wo[nt][1]  = g_load8<FP32>(Wov, wrow + 32);
    const int col = 16 * nt + l16;
    bqf[nt] = g_loadf<FP32>(bqv, col);
    bkf[nt] = g_loadf<FP32>(bkv, col);
    bof[nt] = g_loadf<FP32>(bov, col);
    gf[nt]  = g_loadf<FP32>(lngv, col);
    lbf[nt] = g_loadf<FP32>(lnbv, col);
#pragma unroll
    for (int r = 0; r < 4; ++r)
      bvf[nt][r] = g_loadf<FP32>(bvv, 16 * nt + 4 * q4 + r);
  }

  // Shuffle source lanes for the q4-axis fragment permutation (shared by
  // the P build and the ctx build):
  // target (q4,l16) dword j pulls from lane (2*(q4&1) + (j>>1), l16).
  const int srcA = ((lane & 16) << 1) | l16;  // q4' = 2*(q4&1)
  const int srcB = srcA + 16;                 // q4' = 2*(q4&1)+1
  const bool hsel = (lane & 32) != 0;         // h / dt-low selector = q4>>1

  // =================== Persistent loop over 4 (b,i) tiles ==================
#pragma unroll 1
  for (int bi = blockIdx.x; bi < 1024; bi += 256) {
    const size_t xoff = (size_t)bi * 16384;

    // ---------------- Phase 1 (merged): Q,K,V^T ----------------------------
    // X prefetch: all 4 mt tiles issued up front (one latency exposure).
    {
      bh8 xf[4][2];
#pragma unroll
      for (int mt = 0; mt < 4; ++mt) {
        const size_t xr = xoff + (size_t)(m0w + 16 * mt + l16) * 64 + 8 * q4;
        xf[mt][0] = g_load8<FP32>(Xv, xr);
        xf[mt][1] = g_load8<FP32>(Xv, xr + 32);
      }
#pragma unroll
      for (int mt = 0; mt < 4; ++mt) {
        // Q projection -> sQ
#pragma unroll
        for (int nt = 0; nt < 4; ++nt) {
          f32x4 acc = {0.f, 0.f, 0.f, 0.f};
          acc = MFMA(xf[mt][0], wq[nt][0], acc);
          acc = MFMA(xf[mt][1], wq[nt][1], acc);
#pragma unroll
          for (int r = 0; r < 4; ++r)
            sQ[(m0w + 16 * mt + 4 * q4 + r) * SQ_STRIDE + 16 * nt + l16] =
                f2bf(acc[r] + bqf[nt]);
        }
        // K projection -> sK
#pragma unroll
        for (int nt = 0; nt < 4; ++nt) {
          f32x4 acc = {0.f, 0.f, 0.f, 0.f};
          acc = MFMA(xf[mt][0], wk[nt][0], acc);
          acc = MFMA(xf[mt][1], wk[nt][1], acc);
#pragma unroll
          for (int r = 0; r < 4; ++r)
            sK[(m0w + 16 * mt + 4 * q4 + r) * SQ_STRIDE + 16 * nt + l16] =
                f2bf(acc[r] + bkf[nt]);
        }
        // V^T projection -> sVt
#pragma unroll
        for (int dt = 0; dt < 4; ++dt) {
          f32x4 acc = {0.f, 0.f, 0.f, 0.f};
          acc = MFMA(wvv[dt][0], xf[mt][0], acc);
          acc = MFMA(wvv[dt][1], xf[mt][1], acc);
#pragma unroll
          for (int r = 0; r < 4; ++r)
            sVt[(16 * dt + 4 * q4 + r) * SVT_STRIDE + m0w + 16 * mt + l16] =
                f2bf(acc[r] + bvf[dt][r]);
        }
      }
    }
    __syncthreads();  // sQ/sK/sVt valid block-wide

    // V-fragment hoist: vf depends only on (ct,dt) -- load ONCE per tile
    // (was re-read every mt: 128 ds_read_b128 -> 32). +128 VGPR.
    bh8 vfr[8][4];
#pragma unroll
    for (int ct = 0; ct < 8; ++ct)
#pragma unroll
      for (int dt = 0; dt < 4; ++dt)
        vfr[ct][dt] =
            *(const bh8*)(sVt + (16 * dt + l16) * SVT_STRIDE + 32 * ct + 8 * q4);

    // ---------------- Phase 2: fused S -> P -> PV -> out -> LN -------------
#pragma unroll 1
    for (int mt = 0; mt < 4; ++mt) {
      const int a0 = m0w + 16 * mt;
      const unsigned short* krow = sK + (a0 + l16) * SQ_STRIDE + 8 * q4;
      bh8 kf0 = *(const bh8*)(krow);
      bh8 kf1 = *(const bh8*)(krow + 32);

      // Residual X loads hoisted: latency hides under the ct chain below.
      float xres[4][4];
#pragma unroll
      for (int nt = 0; nt < 4; ++nt)
#pragma unroll
        for (int r = 0; r < 4; ++r)
          xres[nt][r] = g_loadf<FP32>(
              Xv, xoff + (size_t)(a0 + 4 * q4 + r) * 64 + 16 * nt + l16);

      f32x4 ctxa[4];
#pragma unroll
      for (int dt = 0; dt < 4; ++dt) ctxa[dt] = (f32x4){0.f, 0.f, 0.f, 0.f};
      float rs = 0.f;  // row-sum for row a = a0+l16 (lane-local partial)

      // FULLY unrolled (static vfr indexing); barrier-free.
#pragma unroll
      for (int ct = 0; ct < 8; ++ct) {
        // Swapped QK^T: s[r] = S[c0+4*q4+r][a0+l16]
        int ph0[2], ph1[2];
#pragma unroll
        for (int h = 0; h < 2; ++h) {
          const int c0 = 32 * ct + 16 * h;
          const unsigned short* qrow = sQ + (c0 + l16) * SQ_STRIDE + 8 * q4;
          bh8 qf0 = *(const bh8*)(qrow);
          bh8 qf1 = *(const bh8*)(qrow + 32);
          f32x4 s = {0.f, 0.f, 0.f, 0.f};
          s = MFMA(qf0, kf0, s);
          s = MFMA(qf1, kf1, s);
          float v0 = fmaxf(s[0] * 0.125f, 0.f);
          float v1 = fmaxf(s[1] * 0.125f, 0.f);
          float v2 = fmaxf(s[2] * 0.125f, 0.f);
          float v3 = fmaxf(s[3] * 0.125f, 0.f);
          rs += (v0 + v1) + (v2 + v3);
          if (h == 0) { ph0[0] = pkbf(v0, v1); ph0[1] = pkbf(v2, v3); }
          else        { ph1[0] = pkbf(v0, v1); ph1[1] = pkbf(v2, v3); }
        }
        // Build PV B-fragment in-register (no LDS, no barrier).
        union { int d[4]; bh8 v; } pfu;
#pragma unroll
        for (int j = 0; j < 4; ++j) {
          const int srcl = (j < 2) ? srcA : srcB;
          int t0, t1;
          if ((j & 1) == 0) { t0 = __shfl(ph0[0], srcl); t1 = __shfl(ph1[0], srcl); }
          else              { t0 = __shfl(ph0[1], srcl); t1 = __shfl(ph1[1], srcl); }
          pfu.d[j] = hsel ? t1 : t0;
        }
#pragma unroll
        for (int dt = 0; dt < 4; ++dt)
          ctxa[dt] = MFMA(vfr[ct][dt], pfu.v, ctxa[dt]);  // ctx^T[d][a]
      }

      // denom = sum_c relu + M*1e-12 (reference adds 1e-12 inside the sum)
      rs += __shfl_xor(rs, 16);
      rs += __shfl_xor(rs, 32);
      const float inv = 1.f / (rs + 2.56e-10f);

      // ctx^T -> out-proj A-fragment IN-REGISTER (same permutation class as
      // the P build). dt = q4>>1 (+2 for cf1), q4' = 2(q4&1)+(j>>1), pack=j&1.
      int pc[4][2];
#pragma unroll
      for (int dt = 0; dt < 4; ++dt) {
        pc[dt][0] = pkbf(ctxa[dt][0] * inv, ctxa[dt][1] * inv);
        pc[dt][1] = pkbf(ctxa[dt][2] * inv, ctxa[dt][3] * inv);
      }
      union { int d[4]; bh8 v; } cf0u, cf1u;
#pragma unroll
      for (int j = 0; j < 4; ++j) {
        const int srcl = (j < 2) ? srcA : srcB;
        const int jp = j & 1;
        int t0 = __shfl(pc[0][jp], srcl);
        int t1 = __shfl(pc[1][jp], srcl);
        int t2 = __shfl(pc[2][jp], srcl);
        int t3 = __shfl(pc[3][jp], srcl);
        cf0u.d[j] = hsel ? t1 : t0;
        cf1u.d[j] = hsel ? t3 : t2;
      }

      float yv[4][4];
      float s1[4] = {0.f, 0.f, 0.f, 0.f};
      float s2[4] = {0.f, 0.f, 0.f, 0.f};
#pragma unroll
      for (int nt = 0; nt < 4; ++nt) {
        f32x4 o = {0.f, 0.f, 0.f, 0.f};
        o = MFMA(cf0u.v, wo[nt][0], o);
        o = MFMA(cf1u.v, wo[nt][1], o);
#pragma unroll
        for (int r = 0; r < 4; ++r) {
          float y = o[r] + bof[nt] + xres[nt][r];
          yv[nt][r] = y;
          s1[r] += y;
          s2[r] += y * y;
        }
      }
#pragma unroll
      for (int r = 0; r < 4; ++r) {
        s1[r] += __shfl_xor(s1[r], 1);
        s1[r] += __shfl_xor(s1[r], 2);
        s1[r] += __shfl_xor(s1[r], 4);
        s1[r] += __shfl_xor(s1[r], 8);
        s2[r] += __shfl_xor(s2[r], 1);
        s2[r] += __shfl_xor(s2[r], 2);
        s2[r] += __shfl_xor(s2[r], 4);
        s2[r] += __shfl_xor(s2[r], 8);
        const float mu   = s1[r] * 0.015625f;
        const float var  = s2[r] * 0.015625f - mu * mu;
        const float rstd = rsqrtf(var + 1e-5f);
        if constexpr (FP32) {
          float* Outf = (float*)Outv;
#pragma unroll
          for (int nt = 0; nt < 4; ++nt)
            Outf[xoff + (size_t)(a0 + 4 * q4 + r) * 64 + 16 * nt + l16] =
                (yv[nt][r] - mu) * rstd * gf[nt] + lbf[nt];
        } else {
#pragma unroll
          for (int nt = 0; nt < 4; ++nt)
            stg[(4 * q4 + r) * SY_STRIDE + 16 * nt + l16] =
                f2bf((yv[nt][r] - mu) * rstd * gf[nt] + lbf[nt]);
        }
      }
      if constexpr (!FP32) {
        __syncthreads();  // insurance: y stage write -> read
        const int row = lane >> 2, seg = lane & 3;
        const unsigned short* yr = stg + row * SY_STRIDE + seg * 8;
        uint4 u0 = *(const uint4*)(yr);
        uint4 u1 = *(const uint4*)(yr + 32);
        unsigned short* orow =
            (unsigned short*)Outv + xoff + (size_t)(a0 + row) * 64 + seg * 8;
        *(uint4*)(orow)      = u0;
        *(uint4*)(orow + 32) = u1;
      }
    }
    __syncthreads();  // end-of-tile: protect sQ/sK/sVt WAR for next bi
  }
}

extern "C" void kernel_launch(void* const* d_in, const int* in_sizes, int n_in,
                              void* d_out, int out_size, void* d_ws, size_t ws_size,
                              hipStream_t stream) {
  (void)n_in; (void)d_ws; (void)ws_size; (void)out_size;
  const void* X  = d_in[1];   // structure_matrix (d_in[0]=hidden_states unused)
  const void* Wq = d_in[2];  const void* bq = d_in[3];
  const void* Wk = d_in[4];  const void* bk = d_in[5];
  const void* Wv = d_in[6];  const void* bv = d_in[7];
  const void* Wo = d_in[8];  const void* bo = d_in[9];
  const void* lg = d_in[10]; const void* lb = d_in[11];

  // Host-side dtype dispatch: structure_matrix has 4*256*256*64 = 16777216
  // elements. If in_sizes[1] is a byte count it identifies the dtype and we
  // launch ONE kernel; any other value -> launch both (device sniff makes
  // the wrong one exit early, as before).
  const long long NELT = 16777216LL;
  const long long sz1  = (long long)in_sizes[1];
  bool want_bf16 = true, want_f32 = true;
  if (sz1 == NELT * 2) want_f32 = false;        // bf16 bytes
  else if (sz1 == NELT * 4) want_bf16 = false;  // fp32 bytes

  auto k0 = pairattn<0>;  // bf16 inputs/outputs
  auto k1 = pairattn<1>;  // fp32 inputs/outputs
  if (want_bf16) {
    hipFuncSetAttribute((const void*)k0, hipFuncAttributeMaxDynamicSharedMemorySize, LDS_BYTES);
    k0<<<256, 256, LDS_BYTES, stream>>>(X, Wq, bq, Wk, bk, Wv, bv, Wo, bo, lg, lb, d_out);
  }
  if (want_f32) {
    hipFuncSetAttribute((const void*)k1, hipFuncAttributeMaxDynamicSharedMemorySize, LDS_BYTES);
    k1<<<256, 256, LDS_BYTES, stream>>>(X, Wq, bq, Wk, bk, Wv, bv, Wo, bo, lg, lb, d_out);
  }
}

// Round 15
// 208.877 us; speedup vs baseline: 1.1307x; 1.0513x over previous
//
#include <hip/hip_runtime.h>

// ---------------------------------------------------------------------------
// SelfAttentionPairDim2: B=4, N=256, M=256, D=64. Output [4,256,256,64].
// PERSISTENT blocks: grid 256 (=CU count), each block processes 4 (b,i)
// tiles. Fused MFMA pipeline per tile:
//   QKV proj -> S=relu(K Q^T/8) -> rownorm -> P V -> out proj -> +x -> LN
//
// R15: phase-2 LOOP INTERCHANGE (ct outer/rolled, mt inner/unrolled).
// R14 proved LDS-traffic reduction pays (V-hoist: conflicts 6.95M->3.80M,
// metric 227->219.6). Q reads had the same mt-redundancy (128 b128/tile
// where 32 suffice). Interchange amortizes BOTH Q and V across mt without
// R14's 128-VGPR vfr array: per ct, 4 Q + 4 V b128 reads feed all 4 mt's
// MFMAs. Per-tile b128: 168 -> 72 (K8+Q32+V32). Bonus: 8 independent QK
// MFMAs per ct slot (4x ILP at 1 wave/SIMD). State: ctxa[4][4], rs[4],
// kf[4][2] -- static-indexed via full mt unroll (runtime-indexed reg
// arrays spill). Numerics identical (same ct accumulation order).
// Ledger: preload/amortize done (R6/R10/R12/R14 wins; R11/R13 neutral);
// unroll-2/warmx/cache-warmth dead; trust bench metric (hot +-20% noise).
// Frozen: 256 thr / 4 waves / 1 block/CU (any >1 wave/SIMD fails O(1),
// mechanism unknown -- R1/R2/R3/R5).
// ---------------------------------------------------------------------------

using bh8   = __attribute__((ext_vector_type(8))) short;
using f32x4 = __attribute__((ext_vector_type(4))) float;

#define MFMA(a, b, c) __builtin_amdgcn_mfma_f32_16x16x32_bf16((a), (b), (c), 0, 0, 0)

#define SQ_STRIDE  72   // elements; 144 B rows (16B aligned)
#define SVT_STRIDE 264  // elements; 528 B rows (16B aligned)
#define SY_STRIDE  72
#define STG_ELTS   (16 * 72)  // 1152 per wave (y staging only)
#define LDS_BYTES  ((256 * SQ_STRIDE * 2 + 64 * SVT_STRIDE + 4 * STG_ELTS) * 2)  // 116736 B

__device__ __forceinline__ float bf2f(unsigned short u) {
  union { unsigned int i; float f; } x;
  x.i = ((unsigned int)u) << 16;
  return x.f;
}
__device__ __forceinline__ unsigned short f2bf(float f) {
  union { float f; unsigned int i; } x;
  x.f = f;
  unsigned int u = x.i + 0x7FFFu + ((x.i >> 16) & 1u);  // RNE
  return (unsigned short)(u >> 16);
}
__device__ __forceinline__ int pkbf(float lo, float hi) {
  return (int)(((unsigned int)f2bf(hi) << 16) | (unsigned int)f2bf(lo));
}

template <int FP32>
__device__ __forceinline__ bh8 g_load8(const void* base, size_t idx) {
  if constexpr (FP32) {
    const float* p = (const float*)base + idx;
    float4 a = *(const float4*)p;
    float4 b = *(const float4*)(p + 4);
    bh8 r;
    r[0] = (short)f2bf(a.x); r[1] = (short)f2bf(a.y);
    r[2] = (short)f2bf(a.z); r[3] = (short)f2bf(a.w);
    r[4] = (short)f2bf(b.x); r[5] = (short)f2bf(b.y);
    r[6] = (short)f2bf(b.z); r[7] = (short)f2bf(b.w);
    return r;
  } else {
    return *(const bh8*)((const unsigned short*)base + idx);
  }
}
template <int FP32>
__device__ __forceinline__ float g_loadf(const void* base, size_t idx) {
  if constexpr (FP32) return ((const float*)base)[idx];
  else return bf2f(((const unsigned short*)base)[idx]);
}

template <int FP32>
__global__ __launch_bounds__(256, 1) void pairattn(
    const void* __restrict__ Xv,
    const void* __restrict__ Wqv, const void* __restrict__ bqv,
    const void* __restrict__ Wkv, const void* __restrict__ bkv,
    const void* __restrict__ Wvv, const void* __restrict__ bvv,
    const void* __restrict__ Wov, const void* __restrict__ bov,
    const void* __restrict__ lngv, const void* __restrict__ lnbv,
    void* __restrict__ Outv) {
  const int tid  = threadIdx.x;
  const int lane = tid & 63;

  // ---- dtype detection (block-uniform, deterministic; guard for the
  // dual-launch fallback path) ----
  {
    const unsigned short* xu = (const unsigned short*)Xv + (lane << 4);
    int huge = 0;
#pragma unroll
    for (int j = 0; j < 16; ++j) {
      unsigned e = ((unsigned)xu[j] >> 7) & 0xFFu;
      huge |= (e >= 0x90u) ? 1 : 0;
    }
    const bool isf32 = (__ballot(huge) != 0ULL);
    if (isf32 != (FP32 != 0)) return;  // uniform exit, before any barrier
  }

  extern __shared__ unsigned short sm[];
  unsigned short* sQ  = sm;                        // 256 x 72
  unsigned short* sK  = sQ + 256 * SQ_STRIDE;      // 256 x 72
  unsigned short* sVt = sK + 256 * SQ_STRIDE;      // 64 x 264 (V transposed)
  unsigned short* sSt = sVt + 64 * SVT_STRIDE;     // 4 x 1152 wave-private

  const int wv  = tid >> 6;
  const int q4  = lane >> 4;
  const int l16 = lane & 15;
  const int m0w = wv << 6;
  unsigned short* stg = sSt + wv * STG_ELTS;

  // ---- One-time preloads (amortized over 4 tiles) -------------------------
  bh8 wq[4][2], wk[4][2], wvv[4][2], wo[4][2];
  float bqf[4], bkf[4], bvf[4][4], bof[4], gf[4], lbf[4];
#pragma unroll
  for (int nt = 0; nt < 4; ++nt) {
    const int wrow = (16 * nt + l16) * 64 + 8 * q4;
    wq[nt][0]  = g_load8<FP32>(Wqv, wrow);
    wq[nt][1]  = g_load8<FP32>(Wqv, wrow + 32);
    wk[nt][0]  = g_load8<FP32>(Wkv, wrow);
    wk[nt][1]  = g_load8<FP32>(Wkv, wrow + 32);
    wvv[nt][0] = g_load8<FP32>(Wvv, wrow);
    wvv[nt][1] = g_load8<FP32>(Wvv, wrow + 32);
    wo[nt][0]  = g_load8<FP32>(Wov, wrow);
    wo[nt][1]  = g_load8<FP32>(Wov, wrow + 32);
    const int col = 16 * nt + l16;
    bqf[nt] = g_loadf<FP32>(bqv, col);
    bkf[nt] = g_loadf<FP32>(bkv, col);
    bof[nt] = g_loadf<FP32>(bov, col);
    gf[nt]  = g_loadf<FP32>(lngv, col);
    lbf[nt] = g_loadf<FP32>(lnbv, col);
#pragma unroll
    for (int r = 0; r < 4; ++r)
      bvf[nt][r] = g_loadf<FP32>(bvv, 16 * nt + 4 * q4 + r);
  }

  // Shuffle source lanes for the q4-axis fragment permutation (shared by
  // the P build and the ctx build):
  // target (q4,l16) dword j pulls from lane (2*(q4&1) + (j>>1), l16).
  const int srcA = ((lane & 16) << 1) | l16;  // q4' = 2*(q4&1)
  const int srcB = srcA + 16;                 // q4' = 2*(q4&1)+1
  const bool hsel = (lane & 32) != 0;         // h / dt-low selector = q4>>1

  // =================== Persistent loop over 4 (b,i) tiles ==================
#pragma unroll 1
  for (int bi = blockIdx.x; bi < 1024; bi += 256) {
    const size_t xoff = (size_t)bi * 16384;

    // ---------------- Phase 1 (merged): Q,K,V^T ----------------------------
    // X prefetch: all 4 mt tiles issued up front (one latency exposure).
    {
      bh8 xf[4][2];
#pragma unroll
      for (int mt = 0; mt < 4; ++mt) {
        const size_t xr = xoff + (size_t)(m0w + 16 * mt + l16) * 64 + 8 * q4;
        xf[mt][0] = g_load8<FP32>(Xv, xr);
        xf[mt][1] = g_load8<FP32>(Xv, xr + 32);
      }
#pragma unroll
      for (int mt = 0; mt < 4; ++mt) {
        // Q projection -> sQ
#pragma unroll
        for (int nt = 0; nt < 4; ++nt) {
          f32x4 acc = {0.f, 0.f, 0.f, 0.f};
          acc = MFMA(xf[mt][0], wq[nt][0], acc);
          acc = MFMA(xf[mt][1], wq[nt][1], acc);
#pragma unroll
          for (int r = 0; r < 4; ++r)
            sQ[(m0w + 16 * mt + 4 * q4 + r) * SQ_STRIDE + 16 * nt + l16] =
                f2bf(acc[r] + bqf[nt]);
        }
        // K projection -> sK
#pragma unroll
        for (int nt = 0; nt < 4; ++nt) {
          f32x4 acc = {0.f, 0.f, 0.f, 0.f};
          acc = MFMA(xf[mt][0], wk[nt][0], acc);
          acc = MFMA(xf[mt][1], wk[nt][1], acc);
#pragma unroll
          for (int r = 0; r < 4; ++r)
            sK[(m0w + 16 * mt + 4 * q4 + r) * SQ_STRIDE + 16 * nt + l16] =
                f2bf(acc[r] + bkf[nt]);
        }
        // V^T projection -> sVt
#pragma unroll
        for (int dt = 0; dt < 4; ++dt) {
          f32x4 acc = {0.f, 0.f, 0.f, 0.f};
          acc = MFMA(wvv[dt][0], xf[mt][0], acc);
          acc = MFMA(wvv[dt][1], xf[mt][1], acc);
#pragma unroll
          for (int r = 0; r < 4; ++r)
            sVt[(16 * dt + 4 * q4 + r) * SVT_STRIDE + m0w + 16 * mt + l16] =
                f2bf(acc[r] + bvf[dt][r]);
        }
      }
    }
    __syncthreads();  // sQ/sK/sVt valid block-wide

    // K fragments for all 4 mt (8 ds_read_b128, once per tile).
    bh8 kf[4][2];
#pragma unroll
    for (int mt = 0; mt < 4; ++mt) {
      const unsigned short* krow =
          sK + (m0w + 16 * mt + l16) * SQ_STRIDE + 8 * q4;
      kf[mt][0] = *(const bh8*)(krow);
      kf[mt][1] = *(const bh8*)(krow + 32);
    }

    // ---------------- Phase 2a: S -> P -> PV, ct outer / mt inner ----------
    // Per ct: 4 Q + 4 V b128 reads shared by all 4 mt (was per-mt re-read);
    // 8 independent QK MFMAs + 16 PV MFMAs per ct slot.
    f32x4 ctxa[4][4];  // [mt][dt]
    float rs[4] = {0.f, 0.f, 0.f, 0.f};
#pragma unroll
    for (int mt = 0; mt < 4; ++mt)
#pragma unroll
      for (int dt = 0; dt < 4; ++dt) ctxa[mt][dt] = (f32x4){0.f, 0.f, 0.f, 0.f};

#pragma unroll 1
    for (int ct = 0; ct < 8; ++ct) {
      bh8 qf[2][2];
#pragma unroll
      for (int h = 0; h < 2; ++h) {
        const unsigned short* qrow =
            sQ + (32 * ct + 16 * h + l16) * SQ_STRIDE + 8 * q4;
        qf[h][0] = *(const bh8*)(qrow);
        qf[h][1] = *(const bh8*)(qrow + 32);
      }
      bh8 vf[4];
#pragma unroll
      for (int dt = 0; dt < 4; ++dt)
        vf[dt] =
            *(const bh8*)(sVt + (16 * dt + l16) * SVT_STRIDE + 32 * ct + 8 * q4);

#pragma unroll
      for (int mt = 0; mt < 4; ++mt) {
        // Swapped QK^T: s[r] = S[32ct+16h+4*q4+r][m0w+16mt+l16]
        int ph0[2], ph1[2];
#pragma unroll
        for (int h = 0; h < 2; ++h) {
          f32x4 s = {0.f, 0.f, 0.f, 0.f};
          s = MFMA(qf[h][0], kf[mt][0], s);
          s = MFMA(qf[h][1], kf[mt][1], s);
          float v0 = fmaxf(s[0] * 0.125f, 0.f);
          float v1 = fmaxf(s[1] * 0.125f, 0.f);
          float v2 = fmaxf(s[2] * 0.125f, 0.f);
          float v3 = fmaxf(s[3] * 0.125f, 0.f);
          rs[mt] += (v0 + v1) + (v2 + v3);
          if (h == 0) { ph0[0] = pkbf(v0, v1); ph0[1] = pkbf(v2, v3); }
          else        { ph1[0] = pkbf(v0, v1); ph1[1] = pkbf(v2, v3); }
        }
        // Build PV B-fragment in-register (no LDS, no barrier).
        union { int d[4]; bh8 v; } pfu;
#pragma unroll
        for (int j = 0; j < 4; ++j) {
          const int srcl = (j < 2) ? srcA : srcB;
          int t0, t1;
          if ((j & 1) == 0) { t0 = __shfl(ph0[0], srcl); t1 = __shfl(ph1[0], srcl); }
          else              { t0 = __shfl(ph0[1], srcl); t1 = __shfl(ph1[1], srcl); }
          pfu.d[j] = hsel ? t1 : t0;
        }
#pragma unroll
        for (int dt = 0; dt < 4; ++dt)
          ctxa[mt][dt] = MFMA(vf[dt], pfu.v, ctxa[mt][dt]);  // ctx^T[d][a]
      }
    }

    // ---------------- Phase 2b: per-mt epilogue ----------------------------
#pragma unroll
    for (int mt = 0; mt < 4; ++mt) {
      const int a0 = m0w + 16 * mt;

      // Residual X loads issued early (cover: rs reduce + pc + shuffles).
      float xres[4][4];
#pragma unroll
      for (int nt = 0; nt < 4; ++nt)
#pragma unroll
        for (int r = 0; r < 4; ++r)
          xres[nt][r] = g_loadf<FP32>(
              Xv, xoff + (size_t)(a0 + 4 * q4 + r) * 64 + 16 * nt + l16);

      // denom = sum_c relu + M*1e-12 (reference adds 1e-12 inside the sum)
      float rsm = rs[mt];
      rsm += __shfl_xor(rsm, 16);
      rsm += __shfl_xor(rsm, 32);
      const float inv = 1.f / (rsm + 2.56e-10f);

      // ctx^T -> out-proj A-fragment IN-REGISTER (same permutation class as
      // the P build). dt = q4>>1 (+2 for cf1), q4' = 2(q4&1)+(j>>1), pack=j&1.
      int pc[4][2];
#pragma unroll
      for (int dt = 0; dt < 4; ++dt) {
        pc[dt][0] = pkbf(ctxa[mt][dt][0] * inv, ctxa[mt][dt][1] * inv);
        pc[dt][1] = pkbf(ctxa[mt][dt][2] * inv, ctxa[mt][dt][3] * inv);
      }
      union { int d[4]; bh8 v; } cf0u, cf1u;
#pragma unroll
      for (int j = 0; j < 4; ++j) {
        const int srcl = (j < 2) ? srcA : srcB;
        const int jp = j & 1;
        int t0 = __shfl(pc[0][jp], srcl);
        int t1 = __shfl(pc[1][jp], srcl);
        int t2 = __shfl(pc[2][jp], srcl);
        int t3 = __shfl(pc[3][jp], srcl);
        cf0u.d[j] = hsel ? t1 : t0;
        cf1u.d[j] = hsel ? t3 : t2;
      }

      float yv[4][4];
      float s1[4] = {0.f, 0.f, 0.f, 0.f};
      float s2[4] = {0.f, 0.f, 0.f, 0.f};
#pragma unroll
      for (int nt = 0; nt < 4; ++nt) {
        f32x4 o = {0.f, 0.f, 0.f, 0.f};
        o = MFMA(cf0u.v, wo[nt][0], o);
        o = MFMA(cf1u.v, wo[nt][1], o);
#pragma unroll
        for (int r = 0; r < 4; ++r) {
          float y = o[r] + bof[nt] + xres[nt][r];
          yv[nt][r] = y;
          s1[r] += y;
          s2[r] += y * y;
        }
      }
#pragma unroll
      for (int r = 0; r < 4; ++r) {
        s1[r] += __shfl_xor(s1[r], 1);
        s1[r] += __shfl_xor(s1[r], 2);
        s1[r] += __shfl_xor(s1[r], 4);
        s1[r] += __shfl_xor(s1[r], 8);
        s2[r] += __shfl_xor(s2[r], 1);
        s2[r] += __shfl_xor(s2[r], 2);
        s2[r] += __shfl_xor(s2[r], 4);
        s2[r] += __shfl_xor(s2[r], 8);
        const float mu   = s1[r] * 0.015625f;
        const float var  = s2[r] * 0.015625f - mu * mu;
        const float rstd = rsqrtf(var + 1e-5f);
        if constexpr (FP32) {
          float* Outf = (float*)Outv;
#pragma unroll
          for (int nt = 0; nt < 4; ++nt)
            Outf[xoff + (size_t)(a0 + 4 * q4 + r) * 64 + 16 * nt + l16] =
                (yv[nt][r] - mu) * rstd * gf[nt] + lbf[nt];
        } else {
#pragma unroll
          for (int nt = 0; nt < 4; ++nt)
            stg[(4 * q4 + r) * SY_STRIDE + 16 * nt + l16] =
                f2bf((yv[nt][r] - mu) * rstd * gf[nt] + lbf[nt]);
        }
      }
      if constexpr (!FP32) {
        __syncthreads();  // insurance: y stage write -> read
        const int row = lane >> 2, seg = lane & 3;
        const unsigned short* yr = stg + row * SY_STRIDE + seg * 8;
        uint4 u0 = *(const uint4*)(yr);
        uint4 u1 = *(const uint4*)(yr + 32);
        unsigned short* orow =
            (unsigned short*)Outv + xoff + (size_t)(a0 + row) * 64 + seg * 8;
        *(uint4*)(orow)      = u0;
        *(uint4*)(orow + 32) = u1;
      }
    }
    __syncthreads();  // end-of-tile: protect sQ/sK/sVt WAR for next bi
  }
}

extern "C" void kernel_launch(void* const* d_in, const int* in_sizes, int n_in,
                              void* d_out, int out_size, void* d_ws, size_t ws_size,
                              hipStream_t stream) {
  (void)n_in; (void)d_ws; (void)ws_size; (void)out_size;
  const void* X  = d_in[1];   // structure_matrix (d_in[0]=hidden_states unused)
  const void* Wq = d_in[2];  const void* bq = d_in[3];
  const void* Wk = d_in[4];  const void* bk = d_in[5];
  const void* Wv = d_in[6];  const void* bv = d_in[7];
  const void* Wo = d_in[8];  const void* bo = d_in[9];
  const void* lg = d_in[10]; const void* lb = d_in[11];

  // Host-side dtype dispatch: structure_matrix has 4*256*256*64 = 16777216
  // elements. If in_sizes[1] is a byte count it identifies the dtype and we
  // launch ONE kernel; any other value -> launch both (device sniff makes
  // the wrong one exit early, as before).
  const long long NELT = 16777216LL;
  const long long sz1  = (long long)in_sizes[1];
  bool want_bf16 = true, want_f32 = true;
  if (sz1 == NELT * 2) want_f32 = false;        // bf16 bytes
  else if (sz1 == NELT * 4) want_bf16 = false;  // fp32 bytes

  auto k0 = pairattn<0>;  // bf16 inputs/outputs
  auto k1 = pairattn<1>;  // fp32 inputs/outputs
  if (want_bf16) {
    hipFuncSetAttribute((const void*)k0, hipFuncAttributeMaxDynamicSharedMemorySize, LDS_BYTES);
    k0<<<256, 256, LDS_BYTES, stream>>>(X, Wq, bq, Wk, bk, Wv, bv, Wo, bo, lg, lb, d_out);
  }
  if (want_f32) {
    hipFuncSetAttribute((const void*)k1, hipFuncAttributeMaxDynamicSharedMemorySize, LDS_BYTES);
    k1<<<256, 256, LDS_BYTES, stream>>>(X, Wq, bq, Wk, bk, Wv, bv, Wo, bo, lg, lb, d_out);
  }
}